// Round 8
// baseline (139.711 us; speedup 1.0000x reference)
//
#include <hip/hip_runtime.h>
#include <math.h>

#define D_FEAT 64
#define RUN 4  // contiguous nodes per wave

// Edge-parallel CSR row-offset build (never in top-5 dispatches).
__global__ void build_starts_kernel(const int* __restrict__ seg,
                                    int* __restrict__ starts,
                                    int nE, int nN) {
    int e = blockIdx.x * blockDim.x + threadIdx.x;
    if (e >= nE) return;
    int s = seg[e];
    int sprev = (e == 0) ? -1 : seg[e - 1];
    for (int v = sprev + 1; v <= s; ++v) starts[v] = e;
    if (e == nE - 1) {
        for (int v = s + 1; v <= nN; ++v) starts[v] = nE;
    }
}

__device__ __forceinline__ int lower_bound_dev(const int* __restrict__ seg,
                                               int nE, int val) {
    int lo = 0, hi = nE;
    while (lo < hi) {
        int mid = (lo + hi) >> 1;
        if (seg[mid] < val) lo = mid + 1; else hi = mid;
    }
    return lo;
}

// Round-5 structure (best so far: 56.5us): one wave per node, lane=feature,
// SALU control via readlane, saddr gathers (uniform row base + lane*4).
// Polish this round:
//  - RUN=4 contiguous nodes per wave; ONE starts load (lanes 0..4) per run,
//    bounds extracted via readlane -> per-node prologue gone.
//  - pad-to-4 (uniform guard per 4 gathers) instead of pad-to-16:
//    padded gathers 2.29M -> 1.75M.
//  - next node's 64 edge indices prefetched before current fmax chain.
template<bool USE_STARTS>
__global__ __launch_bounds__(256) void seg_max_kernel(
    const float* __restrict__ x, const int* __restrict__ nbr,
    const int* __restrict__ seg, const int* __restrict__ starts,
    float* __restrict__ out, int nE, int nN) {
    int wid  = blockIdx.x * (blockDim.x >> 6) + (threadIdx.x >> 6);
    int lane = threadIdx.x & 63;
    int v0 = wid * RUN;
    if (v0 >= nN) return;
    int nrun = (nN - v0 < RUN) ? (nN - v0) : RUN;

    // One bounds load per run: lane i holds starts[v0+i], i in [0, nrun].
    int bl = 0;
    if (USE_STARTS) {
        if (lane <= nrun) bl = starts[v0 + lane];
    } else {
        if (lane <= nrun) bl = lower_bound_dev(seg, nE, v0 + lane);
    }

    // Software pipeline: current node's (s,e,idxv) held; next node's idx
    // window prefetched before the current fmax chain consumes idxv.
    int sC = __builtin_amdgcn_readlane(bl, 0);
    int eC = __builtin_amdgcn_readlane(bl, 1);
    int idxC = 0;
    if (eC > sC) {
        int kc = sC + lane;
        kc = (kc < eC - 1) ? kc : (eC - 1);
        idxC = __builtin_nontemporal_load(nbr + kc);
    }

    for (int r = 0; r < nrun; ++r) {
        int s = sC, e = eC, idxv = idxC;
        if (r + 1 < nrun) {
            sC = e;  // contiguous nodes share boundaries
            eC = __builtin_amdgcn_readlane(bl, r + 2);
            if (eC > sC) {
                int kc = sC + lane;
                kc = (kc < eC - 1) ? kc : (eC - 1);
                idxC = __builtin_nontemporal_load(nbr + kc);
            }
        }

        float m;
        if (e > s) {
            m = -INFINITY;
            for (int k = s; k < e; k += 64) {
                if (k != s) {  // beyond first window (rare; avg seg len 16)
                    int kc = k + lane;
                    kc = (kc < e - 1) ? kc : (e - 1);
                    idxv = __builtin_nontemporal_load(nbr + kc);
                }
#pragma unroll
                for (int j0 = 0; j0 < 64; j0 += 4) {
                    if (k + j0 < e) {  // uniform (SALU) guard per 4 gathers
                        int r0 = __builtin_amdgcn_readlane(idxv, j0 + 0);
                        int r1 = __builtin_amdgcn_readlane(idxv, j0 + 1);
                        int r2 = __builtin_amdgcn_readlane(idxv, j0 + 2);
                        int r3 = __builtin_amdgcn_readlane(idxv, j0 + 3);
                        // SGPR row base + lane*4 => saddr loads
                        float a = x[((size_t)r0 << 6) + lane];
                        float b = x[((size_t)r1 << 6) + lane];
                        float c = x[((size_t)r2 << 6) + lane];
                        float d = x[((size_t)r3 << 6) + lane];
                        m = fmaxf(m, fmaxf(fmaxf(a, b), fmaxf(c, d)));
                    }
                }
            }
        } else {
            m = 0.0f;  // empty segment -> zeros
        }

        __builtin_nontemporal_store(m, out + (size_t)(v0 + r) * D_FEAT + lane);
    }
}

extern "C" void kernel_launch(void* const* d_in, const int* in_sizes, int n_in,
                              void* d_out, int out_size, void* d_ws, size_t ws_size,
                              hipStream_t stream) {
    const float* x   = (const float*)d_in[0];
    const int*   nbr = (const int*)d_in[1];
    const int*   seg = (const int*)d_in[2];
    float*       out = (float*)d_out;

    int nN = in_sizes[0] / D_FEAT;  // 100000
    int nE = in_sizes[1];           // 1600000

    const int wavesPerBlock = 4;    // 256 threads
    int nWaves = (nN + RUN - 1) / RUN;
    int grid = (nWaves + wavesPerBlock - 1) / wavesPerBlock;

    size_t starts_bytes = (size_t)(nN + 1) * sizeof(int);
    if (ws_size >= starts_bytes) {
        int* starts = (int*)d_ws;
        int bgrid = (nE + 255) / 256;
        hipLaunchKernelGGL(build_starts_kernel, dim3(bgrid), dim3(256), 0, stream,
                           seg, starts, nE, nN);
        hipLaunchKernelGGL((seg_max_kernel<true>), dim3(grid), dim3(256), 0, stream,
                           x, nbr, seg, starts, out, nE, nN);
    } else {
        hipLaunchKernelGGL((seg_max_kernel<false>), dim3(grid), dim3(256), 0, stream,
                           x, nbr, seg, nullptr, out, nE, nN);
    }
}

// Round 10
// 133.164 us; speedup vs baseline: 1.0492x; 1.0492x over previous
//
#include <hip/hip_runtime.h>
#include <math.h>

#define D_FEAT 64

// Edge-parallel CSR row-offset build (never in top-5 dispatches).
__global__ void build_starts_kernel(const int* __restrict__ seg,
                                    int* __restrict__ starts,
                                    int nE, int nN) {
    int e = blockIdx.x * blockDim.x + threadIdx.x;
    if (e >= nE) return;
    int s = seg[e];
    int sprev = (e == 0) ? -1 : seg[e - 1];
    for (int v = sprev + 1; v <= s; ++v) starts[v] = e;
    if (e == nE - 1) {
        for (int v = s + 1; v <= nN; ++v) starts[v] = nE;
    }
}

__device__ __forceinline__ int lower_bound_dev(const int* __restrict__ seg,
                                               int nE, int val) {
    int lo = 0, hi = nE;
    while (lo < hi) {
        int mid = (lo + hi) >> 1;
        if (seg[mid] < val) lo = mid + 1; else hi = mid;
    }
    return lo;
}

// EXACT round-5 structure (best measured: 56.5us) with ONE change:
// the x-row gathers are issued via inline asm `global_load_dword ... sc0`
// (device-coherent load = L1 BYPASS, still allocates/hits in L2).
// Rationale: random 256B rows from 25.6MB -> ~0% L1 hit rate; every gather
// allocates an L1 line-fill and per-CU outstanding-miss handling serializes
// (round-8's depth-4 clusters regressing 56.5->65 while traffic was flat is
// the fingerprint of miss-depth limits). sc0 removes L1 allocation from the
// path; L2 retention (FETCH ~176MB compulsory) must stay unchanged.
// Round-8 lesson kept: uniform guard at 16-gather granularity so each
// cluster issues 16 independent loads before any consumption wait.
template<bool USE_STARTS>
__global__ __launch_bounds__(256) void seg_max_kernel(
    const float* __restrict__ x, const int* __restrict__ nbr,
    const int* __restrict__ seg, const int* __restrict__ starts,
    float* __restrict__ out, int nE, int nN) {
    int wid  = blockIdx.x * (blockDim.x >> 6) + (threadIdx.x >> 6);
    int lane = threadIdx.x & 63;
    if (wid >= nN) return;

    int s, e;
    if (USE_STARTS) {
        s = __builtin_amdgcn_readfirstlane(starts[wid]);
        e = __builtin_amdgcn_readfirstlane(starts[wid + 1]);
    } else {
        s = __builtin_amdgcn_readfirstlane(lower_bound_dev(seg, nE, wid));
        e = __builtin_amdgcn_readfirstlane(lower_bound_dev(seg, nE, wid + 1));
    }

    if (e <= s) {  // empty segment: zeros, don't touch nbr/x
        __builtin_nontemporal_store(0.0f, out + (size_t)wid * D_FEAT + lane);
        return;
    }

    int loff = lane << 2;          // byte offset of this lane's feature
    const int eM1 = e - 1;
    float m = -INFINITY;

    for (int k = s; k < e; k += 64) {
        // One coalesced load of up to 64 edge indices, clamped to e-1
        // (duplicates are free for max).
        int kc = k + lane;
        kc = (kc < eM1) ? kc : eM1;
        int idxv = __builtin_nontemporal_load(nbr + kc);

#pragma unroll
        for (int j0 = 0; j0 < 64; j0 += 16) {
            if (k + j0 < e) {      // uniform (SALU) guard per 16-gather cluster
                float val[16];
#pragma unroll
                for (int j = 0; j < 16; ++j) {
                    // SGPR row index -> SGPR-pair row base; saddr-form load,
                    // sc0 = bypass L1, serve from/allocate in L2.
                    int rj = __builtin_amdgcn_readlane(idxv, j0 + j);
                    const float* rowp = x + ((size_t)rj << 6);
                    asm volatile("global_load_dword %0, %1, %2 sc0"
                                 : "=v"(val[j])
                                 : "v"(loff), "s"(rowp));
                }
                // Wait for all 16 in-flight gathers. The "+v" operands make
                // every val[] a read-write operand of this asm -> the fmax
                // consumers CANNOT be scheduled above it (rule-18 hazard).
                asm volatile("s_waitcnt vmcnt(0)"
                             : "+v"(val[0]), "+v"(val[1]), "+v"(val[2]),
                               "+v"(val[3]), "+v"(val[4]), "+v"(val[5]),
                               "+v"(val[6]), "+v"(val[7]), "+v"(val[8]),
                               "+v"(val[9]), "+v"(val[10]), "+v"(val[11]),
                               "+v"(val[12]), "+v"(val[13]), "+v"(val[14]),
                               "+v"(val[15]));
                __builtin_amdgcn_sched_barrier(0);
                float t0 = fmaxf(fmaxf(val[0], val[1]), fmaxf(val[2], val[3]));
                float t1 = fmaxf(fmaxf(val[4], val[5]), fmaxf(val[6], val[7]));
                float t2 = fmaxf(fmaxf(val[8], val[9]), fmaxf(val[10], val[11]));
                float t3 = fmaxf(fmaxf(val[12], val[13]), fmaxf(val[14], val[15]));
                m = fmaxf(m, fmaxf(fmaxf(t0, t1), fmaxf(t2, t3)));
            }
        }
    }

    // Write-once output: non-temporal store, don't evict x from L2.
    __builtin_nontemporal_store(m, out + (size_t)wid * D_FEAT + lane);
}

extern "C" void kernel_launch(void* const* d_in, const int* in_sizes, int n_in,
                              void* d_out, int out_size, void* d_ws, size_t ws_size,
                              hipStream_t stream) {
    const float* x   = (const float*)d_in[0];
    const int*   nbr = (const int*)d_in[1];
    const int*   seg = (const int*)d_in[2];
    float*       out = (float*)d_out;

    int nN = in_sizes[0] / D_FEAT;  // 100000
    int nE = in_sizes[1];           // 1600000

    const int wavesPerBlock = 4;    // 256 threads
    int grid = (nN + wavesPerBlock - 1) / wavesPerBlock;

    size_t starts_bytes = (size_t)(nN + 1) * sizeof(int);
    if (ws_size >= starts_bytes) {
        int* starts = (int*)d_ws;
        int bgrid = (nE + 255) / 256;
        hipLaunchKernelGGL(build_starts_kernel, dim3(bgrid), dim3(256), 0, stream,
                           seg, starts, nE, nN);
        hipLaunchKernelGGL((seg_max_kernel<true>), dim3(grid), dim3(256), 0, stream,
                           x, nbr, seg, starts, out, nE, nN);
    } else {
        hipLaunchKernelGGL((seg_max_kernel<false>), dim3(grid), dim3(256), 0, stream,
                           x, nbr, seg, nullptr, out, nE, nN);
    }
}

// Round 12
// 132.529 us; speedup vs baseline: 1.0542x; 1.0048x over previous
//
#include <hip/hip_runtime.h>
#include <math.h>

#define D_FEAT 64
typedef float f32x4 __attribute__((ext_vector_type(4)));

// Edge-parallel CSR row-offset build (never in top-5 dispatches).
__global__ void build_starts_kernel(const int* __restrict__ seg,
                                    int* __restrict__ starts,
                                    int nE, int nN) {
    int e = blockIdx.x * blockDim.x + threadIdx.x;
    if (e >= nE) return;
    int s = seg[e];
    int sprev = (e == 0) ? -1 : seg[e - 1];
    for (int v = sprev + 1; v <= s; ++v) starts[v] = e;
    if (e == nE - 1) {
        for (int v = s + 1; v <= nN; ++v) starts[v] = nE;
    }
}

__device__ __forceinline__ int lower_bound_dev(const int* __restrict__ seg,
                                               int nE, int val) {
    int lo = 0, hi = nE;
    while (lo < hi) {
        int mid = (lo + hi) >> 1;
        if (seg[mid] < val) lo = mid + 1; else hi = mid;
    }
    return lo;
}

__device__ __forceinline__ f32x4 vmax4(f32x4 a, f32x4 b) {
    f32x4 r;
    r.x = fmaxf(a.x, b.x); r.y = fmaxf(a.y, b.y);
    r.z = fmaxf(a.z, b.z); r.w = fmaxf(a.w, b.w);
    return r;
}

// Quad-row gather, CLEAN issue-rate test (r6 confounds removed):
//  - one wave = 4 groups x 16 lanes; group g reads row idx[4q+g], each lane
//    a float4 -> one global_load_dwordx4 = 4 rows = 1KB (4x fewer VMEM
//    instrs than r5/r10's one-row-per-dword at identical traffic).
//  - row index to lanes WITHOUT bpermute/vaddr: readlane -> SGPRs, then 3
//    cndmasks (masks loop-invariant: g bits) select per-group row; voffset
//    is 32-bit (row<<8 | sub<<4), saddr = uniform x base.  [r6 used
//    ds_bpermute + 64-bit vaddr -> 39% VALU; this is ~5 VALU/quad]
//  - cluster depth KEPT at 16 edges (4 independent dwordx4 in flight; the
//    r8 lesson: never guard finer than 16 edges).
//  - SALU control, pad-16 clamp, nt stores: unchanged from r10.
template<bool USE_STARTS>
__global__ __launch_bounds__(256) void seg_max_kernel(
    const float* __restrict__ x, const int* __restrict__ nbr,
    const int* __restrict__ seg, const int* __restrict__ starts,
    float* __restrict__ out, int nE, int nN) {
    int wid  = blockIdx.x * (blockDim.x >> 6) + (threadIdx.x >> 6);
    int lane = threadIdx.x & 63;
    if (wid >= nN) return;
    int g   = lane >> 4;                 // row slot within quad (0..3)
    int sub = lane & 15;                 // feature quad: 4*sub..4*sub+3
    unsigned subsh = (unsigned)sub << 4; // byte offset within a 256B row
    bool b1 = (g & 1) != 0;              // loop-invariant select masks
    bool b2 = (g & 2) != 0;
    const char* xb = (const char*)x;

    int s, e;
    if (USE_STARTS) {
        s = __builtin_amdgcn_readfirstlane(starts[wid]);
        e = __builtin_amdgcn_readfirstlane(starts[wid + 1]);
    } else {
        s = __builtin_amdgcn_readfirstlane(lower_bound_dev(seg, nE, wid));
        e = __builtin_amdgcn_readfirstlane(lower_bound_dev(seg, nE, wid + 1));
    }

    f32x4 m;
    if (e > s) {
        m.x = m.y = m.z = m.w = -INFINITY;
        const int eM1 = e - 1;
        for (int k = s; k < e; k += 64) {
            int kc = k + lane;
            kc = (kc < eM1) ? kc : eM1;          // clamp: dups free for max
            int idxv = __builtin_nontemporal_load(nbr + kc);

#pragma unroll
            for (int j0 = 0; j0 < 64; j0 += 16) {
                if (k + j0 < e) {  // uniform guard per 16-edge cluster
                    // 16 row indices to SGPRs.
                    int r0  = __builtin_amdgcn_readlane(idxv, j0 + 0);
                    int r1  = __builtin_amdgcn_readlane(idxv, j0 + 1);
                    int r2  = __builtin_amdgcn_readlane(idxv, j0 + 2);
                    int r3  = __builtin_amdgcn_readlane(idxv, j0 + 3);
                    int r4  = __builtin_amdgcn_readlane(idxv, j0 + 4);
                    int r5  = __builtin_amdgcn_readlane(idxv, j0 + 5);
                    int r6  = __builtin_amdgcn_readlane(idxv, j0 + 6);
                    int r7  = __builtin_amdgcn_readlane(idxv, j0 + 7);
                    int r8  = __builtin_amdgcn_readlane(idxv, j0 + 8);
                    int r9  = __builtin_amdgcn_readlane(idxv, j0 + 9);
                    int r10 = __builtin_amdgcn_readlane(idxv, j0 + 10);
                    int r11 = __builtin_amdgcn_readlane(idxv, j0 + 11);
                    int r12 = __builtin_amdgcn_readlane(idxv, j0 + 12);
                    int r13 = __builtin_amdgcn_readlane(idxv, j0 + 13);
                    int r14 = __builtin_amdgcn_readlane(idxv, j0 + 14);
                    int r15 = __builtin_amdgcn_readlane(idxv, j0 + 15);

                    // Per-group row select: 3 cndmask (masks hoisted).
                    int q0 = b2 ? (b1 ? r3  : r2 ) : (b1 ? r1  : r0 );
                    int q1 = b2 ? (b1 ? r7  : r6 ) : (b1 ? r5  : r4 );
                    int q2 = b2 ? (b1 ? r11 : r10) : (b1 ? r9  : r8 );
                    int q3 = b2 ? (b1 ? r15 : r14) : (b1 ? r13 : r12);

                    // 4 independent 1KB gathers (32-bit voffset, saddr base).
                    f32x4 v0 = *(const f32x4*)(xb + (((unsigned)q0 << 8) | subsh));
                    f32x4 v1 = *(const f32x4*)(xb + (((unsigned)q1 << 8) | subsh));
                    f32x4 v2 = *(const f32x4*)(xb + (((unsigned)q2 << 8) | subsh));
                    f32x4 v3 = *(const f32x4*)(xb + (((unsigned)q3 << 8) | subsh));

                    m = vmax4(m, vmax4(vmax4(v0, v1), vmax4(v2, v3)));
                }
            }
        }
        // Merge the 4 row-slots: lanes {sub,16+sub,32+sub,48+sub} -> g==0.
#pragma unroll
        for (int off = 16; off < 64; off <<= 1) {
            f32x4 o;
            o.x = __shfl_xor(m.x, off, 64);
            o.y = __shfl_xor(m.y, off, 64);
            o.z = __shfl_xor(m.z, off, 64);
            o.w = __shfl_xor(m.w, off, 64);
            m = vmax4(m, o);
        }
    } else {
        m.x = m.y = m.z = m.w = 0.0f;  // empty segment -> zeros
    }

    if (g == 0) {
        __builtin_nontemporal_store(m,
            (f32x4*)(out + (size_t)wid * D_FEAT + (size_t)sub * 4));
    }
}

extern "C" void kernel_launch(void* const* d_in, const int* in_sizes, int n_in,
                              void* d_out, int out_size, void* d_ws, size_t ws_size,
                              hipStream_t stream) {
    const float* x   = (const float*)d_in[0];
    const int*   nbr = (const int*)d_in[1];
    const int*   seg = (const int*)d_in[2];
    float*       out = (float*)d_out;

    int nN = in_sizes[0] / D_FEAT;  // 100000
    int nE = in_sizes[1];           // 1600000

    const int wavesPerBlock = 4;    // 256 threads
    int grid = (nN + wavesPerBlock - 1) / wavesPerBlock;

    size_t starts_bytes = (size_t)(nN + 1) * sizeof(int);
    if (ws_size >= starts_bytes) {
        int* starts = (int*)d_ws;
        int bgrid = (nE + 255) / 256;
        hipLaunchKernelGGL(build_starts_kernel, dim3(bgrid), dim3(256), 0, stream,
                           seg, starts, nE, nN);
        hipLaunchKernelGGL((seg_max_kernel<true>), dim3(grid), dim3(256), 0, stream,
                           x, nbr, seg, starts, out, nE, nN);
    } else {
        hipLaunchKernelGGL((seg_max_kernel<false>), dim3(grid), dim3(256), 0, stream,
                           x, nbr, seg, nullptr, out, nE, nN);
    }
}